// Round 1
// baseline (77.956 us; speedup 1.0000x reference)
//
#include <hip/hip_runtime.h>
#include <hip/hip_bf16.h>
#include <math.h>

#define NROWS 4096
#define DDIM  512
#define INV_TAU 1.25f

typedef __attribute__((ext_vector_type(8))) short short8;
typedef __attribute__((ext_vector_type(4))) float f32x4;

__device__ inline void gload_lds16(const void* g, void* l) {
  __builtin_amdgcn_global_load_lds(
      (const __attribute__((address_space(1))) void*)g,
      (__attribute__((address_space(3))) void*)l, 16, 0, 0);
}

__device__ inline unsigned short f2bf(float f) {
  __hip_bfloat16 h = __float2bfloat16(f);
  return __builtin_bit_cast(unsigned short, h);
}
__device__ inline float bf2f(unsigned short u) {
  return __bfloat162float(__builtin_bit_cast(__hip_bfloat16, u));
}

// ---------------------------------------------------------------------------
// Kernel 1: f32 -> bf16 conversion for v1, v2, W ; zero the nsq accumulators.
// ---------------------------------------------------------------------------
__global__ void convert_kernel(const float* __restrict__ v1,
                               const float* __restrict__ v2,
                               const float* __restrict__ W,
                               unsigned short* __restrict__ v1b,
                               unsigned short* __restrict__ v2b,
                               unsigned short* __restrict__ Wb,
                               float* __restrict__ nsq1,
                               float* __restrict__ nsq2) {
  int idx = blockIdx.x * blockDim.x + threadIdx.x;
  if (idx < NROWS) { nsq1[idx] = 0.f; nsq2[idx] = 0.f; }
  const int TOTV = (NROWS * DDIM) / 4;   // 524288 float4 per embedding matrix
  const int TOTW = (DDIM * DDIM) / 4;    // 65536
  const int total = 2 * TOTV + TOTW;
  const int stride = gridDim.x * blockDim.x;
  for (int i = idx; i < total; i += stride) {
    const float4* src; unsigned short* dst; int j;
    if (i < TOTV)            { src = (const float4*)v1; dst = v1b; j = i; }
    else if (i < 2 * TOTV)   { src = (const float4*)v2; dst = v2b; j = i - TOTV; }
    else                     { src = (const float4*)W;  dst = Wb;  j = i - 2 * TOTV; }
    float4 x = src[j];
    ushort4 o;
    o.x = f2bf(x.x); o.y = f2bf(x.y); o.z = f2bf(x.z); o.w = f2bf(x.w);
    *(ushort4*)&dst[j * 4] = o;
  }
}

// ---------------------------------------------------------------------------
// Shared MFMA core: 128x128 tile, 4 waves (2x2), BK=32, K=512.
// A[M,K], B[N,K] both K-major bf16 (stride 512). C = A * B^T in acc[4][4].
// ---------------------------------------------------------------------------
#define MM_CORE(Ag, Bg)                                                        \
  {                                                                            \
    for (int kt = 0; kt < DDIM; kt += 32) {                                    \
      _Pragma("unroll")                                                        \
      for (int i = 0; i < 2; ++i) {                                            \
        int off = i * 4096 + tid * 16; /* byte offset in 8KB tile */           \
        int row = off >> 6;            /* 64B per row (32 bf16)   */           \
        int kb  = off & 63;                                                    \
        gload_lds16((const char*)((Ag) + row * DDIM + kt) + kb,                \
                    (char*)As + i * 4096 + wid * 1024);                        \
        gload_lds16((const char*)((Bg) + row * DDIM + kt) + kb,                \
                    (char*)Bs + i * 4096 + wid * 1024);                        \
      }                                                                        \
      asm volatile("s_waitcnt vmcnt(0)" ::: "memory");                         \
      __syncthreads();                                                         \
      short8 av[4], bv[4];                                                     \
      _Pragma("unroll")                                                        \
      for (int m = 0; m < 4; ++m)                                              \
        av[m] = *(const short8*)&As[(wm * 64 + m * 16 + l15) * 32 + l4 * 8];   \
      _Pragma("unroll")                                                        \
      for (int n = 0; n < 4; ++n)                                              \
        bv[n] = *(const short8*)&Bs[(wn * 64 + n * 16 + l15) * 32 + l4 * 8];   \
      _Pragma("unroll")                                                        \
      for (int m = 0; m < 4; ++m)                                              \
        _Pragma("unroll")                                                      \
        for (int n = 0; n < 4; ++n)                                            \
          acc[m][n] = __builtin_amdgcn_mfma_f32_16x16x32_bf16(                 \
              av[m], bv[n], acc[m][n], 0, 0, 0);                               \
      __syncthreads();                                                         \
    }                                                                          \
  }

// ---------------------------------------------------------------------------
// Kernel 2: projection GEMM  z = elu(v @ W^T + b), bf16 out, + row sum(z^2).
// grid: (512/128, 4096/128, 2)   block: 256
// ---------------------------------------------------------------------------
__global__ __launch_bounds__(256) void proj_kernel(
    const unsigned short* __restrict__ v1b, const unsigned short* __restrict__ v2b,
    const unsigned short* __restrict__ Wb,  const float* __restrict__ bias,
    unsigned short* __restrict__ z1b, unsigned short* __restrict__ z2b,
    float* __restrict__ nsq1, float* __restrict__ nsq2) {
  __shared__ __align__(16) unsigned short As[128 * 32];
  __shared__ __align__(16) unsigned short Bs[128 * 32];
  const int tid = threadIdx.x;
  const int wid = tid >> 6, lane = tid & 63;
  const int wm = wid >> 1, wn = wid & 1;
  const int l15 = lane & 15, l4 = lane >> 4;

  const int zsel = blockIdx.z;
  const unsigned short* Ag = (zsel ? v2b : v1b) + (size_t)blockIdx.y * 128 * DDIM;
  const unsigned short* Bg = Wb + (size_t)blockIdx.x * 128 * DDIM;
  unsigned short* Z = (zsel ? z2b : z1b);
  float* nsq = (zsel ? nsq2 : nsq1);

  f32x4 acc[4][4];
#pragma unroll
  for (int m = 0; m < 4; ++m)
#pragma unroll
    for (int n = 0; n < 4; ++n) acc[m][n] = (f32x4){0.f, 0.f, 0.f, 0.f};

  MM_CORE(Ag, Bg);

  // epilogue: bias + ELU + bf16 store + row-wise sum of z^2
  const int rowBase = blockIdx.y * 128 + wm * 64;
  const int colBase = blockIdx.x * 128 + wn * 64;
  float bcol[4];
#pragma unroll
  for (int n = 0; n < 4; ++n) bcol[n] = bias[colBase + n * 16 + l15];
#pragma unroll
  for (int m = 0; m < 4; ++m) {
#pragma unroll
    for (int reg = 0; reg < 4; ++reg) {
      int gRow = rowBase + m * 16 + l4 * 4 + reg;
      float rs = 0.f;
#pragma unroll
      for (int n = 0; n < 4; ++n) {
        int gCol = colBase + n * 16 + l15;
        float y = acc[m][n][reg] + bcol[n];
        float zv = (y > 0.f) ? y : expm1f(y);
        unsigned short zb = f2bf(zv);
        Z[(size_t)gRow * DDIM + gCol] = zb;
        float zf = bf2f(zb);
        rs += zf * zf;
      }
      rs += __shfl_xor(rs, 1, 64);
      rs += __shfl_xor(rs, 2, 64);
      rs += __shfl_xor(rs, 4, 64);
      rs += __shfl_xor(rs, 8, 64);
      if (l15 == 0) atomicAdd(&nsq[gRow], rs);
    }
  }
}

// ---------------------------------------------------------------------------
// Kernel 3: dots = z1 @ z2^T with fused exp/cosine/pos-neg-weighted reduction.
// grid: (32, 32)  block: 256.  Writes double2 partial sums per block.
// ---------------------------------------------------------------------------
__global__ __launch_bounds__(256) void dots_kernel(
    const unsigned short* __restrict__ z1b, const unsigned short* __restrict__ z2b,
    const float* __restrict__ nsq1, const float* __restrict__ nsq2,
    const float* __restrict__ pos, const float* __restrict__ neg,
    double* __restrict__ partials) {
  __shared__ __align__(16) unsigned short As[128 * 32];
  __shared__ __align__(16) unsigned short Bs[128 * 32];
  const int tid = threadIdx.x;
  const int wid = tid >> 6, lane = tid & 63;
  const int wm = wid >> 1, wn = wid & 1;
  const int l15 = lane & 15, l4 = lane >> 4;

  const unsigned short* Ag = z1b + (size_t)blockIdx.y * 128 * DDIM;
  const unsigned short* Bg = z2b + (size_t)blockIdx.x * 128 * DDIM;

  f32x4 acc[4][4];
#pragma unroll
  for (int m = 0; m < 4; ++m)
#pragma unroll
    for (int n = 0; n < 4; ++n) acc[m][n] = (f32x4){0.f, 0.f, 0.f, 0.f};

  MM_CORE(Ag, Bg);

  // epilogue: s = exp(dot * rsqrt(n1sq*n2sq) / tau); sums of s*pos, s*(pos+neg)
  const int rowBase = blockIdx.y * 128 + wm * 64;
  const int colBase = blockIdx.x * 128 + wn * 64;
  float n2s[4];
  int gCol[4];
#pragma unroll
  for (int n = 0; n < 4; ++n) {
    gCol[n] = colBase + n * 16 + l15;
    n2s[n] = nsq2[gCol[n]];
  }
  float sumP = 0.f, sumT = 0.f;
#pragma unroll
  for (int m = 0; m < 4; ++m) {
#pragma unroll
    for (int reg = 0; reg < 4; ++reg) {
      int gRow = rowBase + m * 16 + l4 * 4 + reg;
      float r1 = nsq1[gRow];
      const float* prow = pos + (size_t)gRow * NROWS;
      const float* grow = neg + (size_t)gRow * NROWS;
#pragma unroll
      for (int n = 0; n < 4; ++n) {
        float rinv = rsqrtf(r1 * n2s[n]);
        float s = __expf(acc[m][n][reg] * rinv * INV_TAU);
        float p = prow[gCol[n]];
        float g = grow[gCol[n]];
        sumP += s * p;
        sumT += s * (p + g);
      }
    }
  }
#pragma unroll
  for (int sft = 1; sft < 64; sft <<= 1) {
    sumP += __shfl_xor(sumP, sft, 64);
    sumT += __shfl_xor(sumT, sft, 64);
  }
  __shared__ float redP[4], redT[4];
  if (lane == 0) { redP[wid] = sumP; redT[wid] = sumT; }
  __syncthreads();
  if (tid == 0) {
    double tp = (double)redP[0] + redP[1] + redP[2] + redP[3];
    double tt = (double)redT[0] + redT[1] + redT[2] + redT[3];
    int bid = blockIdx.y * gridDim.x + blockIdx.x;
    partials[2 * bid]     = tp;
    partials[2 * bid + 1] = tt;
  }
}

// ---------------------------------------------------------------------------
// Kernel 4: final reduce of 1024 partial pairs -> -log(sumP / sumT)
// ---------------------------------------------------------------------------
__global__ void finalize_kernel(const double* __restrict__ partials,
                                float* __restrict__ out) {
  __shared__ double sp[256], st[256];
  int t = threadIdx.x;
  double a = 0.0, b = 0.0;
  for (int i = t; i < 1024; i += 256) {
    a += partials[2 * i];
    b += partials[2 * i + 1];
  }
  sp[t] = a; st[t] = b;
  __syncthreads();
  for (int s = 128; s > 0; s >>= 1) {
    if (t < s) { sp[t] += sp[t + s]; st[t] += st[t + s]; }
    __syncthreads();
  }
  if (t == 0) out[0] = (float)(log(st[0]) - log(sp[0]));
}

// ---------------------------------------------------------------------------
extern "C" void kernel_launch(void* const* d_in, const int* in_sizes, int n_in,
                              void* d_out, int out_size, void* d_ws, size_t ws_size,
                              hipStream_t stream) {
  (void)in_sizes; (void)n_in; (void)out_size; (void)ws_size;
  const float* v1   = (const float*)d_in[0];
  const float* v2   = (const float*)d_in[1];
  const float* pos  = (const float*)d_in[2];
  const float* neg  = (const float*)d_in[3];
  const float* W    = (const float*)d_in[4];
  const float* bias = (const float*)d_in[5];

  char* ws = (char*)d_ws;
  unsigned short* z1b = (unsigned short*)(ws + 0);         // 4 MiB
  unsigned short* z2b = (unsigned short*)(ws + 4194304);   // 4 MiB
  unsigned short* v1b = (unsigned short*)(ws + 8388608);   // 4 MiB
  unsigned short* v2b = (unsigned short*)(ws + 12582912);  // 4 MiB
  unsigned short* Wb  = (unsigned short*)(ws + 16777216);  // 512 KiB
  float* nsq1         = (float*)(ws + 17301504);           // 16 KiB
  float* nsq2         = (float*)(ws + 17317888);           // 16 KiB
  double* partials    = (double*)(ws + 17334272);          // 16 KiB
  float* out = (float*)d_out;

  hipLaunchKernelGGL(convert_kernel, dim3(1024), dim3(256), 0, stream,
                     v1, v2, W, v1b, v2b, Wb, nsq1, nsq2);
  hipLaunchKernelGGL(proj_kernel, dim3(DDIM / 128, NROWS / 128, 2), dim3(256), 0, stream,
                     v1b, v2b, Wb, bias, z1b, z2b, nsq1, nsq2);
  hipLaunchKernelGGL(dots_kernel, dim3(NROWS / 128, NROWS / 128), dim3(256), 0, stream,
                     z1b, z2b, nsq1, nsq2, pos, neg, partials);
  hipLaunchKernelGGL(finalize_kernel, dim3(1), dim3(256), 0, stream,
                     partials, out);
}